// Round 7
// baseline (982.457 us; speedup 1.0000x reference)
//
#include <hip/hip_runtime.h>
#include <stdint.h>

#define DM 1024
#define NH 16
#define DK 64
#define NB 4
#define SS 2048

// Q pre-scale: (1/sqrt(64)) * log2(e) so scores are in log2 domain.
#define QSCALE 0.18033688011112042f

typedef float f32x4 __attribute__((ext_vector_type(4)));
typedef short s16x8 __attribute__((ext_vector_type(8)));

typedef __attribute__((address_space(1))) unsigned int glb_u32;
typedef __attribute__((address_space(3))) unsigned int lds_u32;

static __device__ __forceinline__ void gload16(const void* g, void* lds) {
  __builtin_amdgcn_global_load_lds((glb_u32*)g, (lds_u32*)lds, 16, 0, 0);
}

static __device__ __forceinline__ unsigned short f2bf(float f) {
  union { float f; unsigned int u; } v;
  v.f = f;
  unsigned int u = v.u + 0x7fffu + ((v.u >> 16) & 1u);  // RNE
  return (unsigned short)(u >> 16);
}

static __device__ __forceinline__ unsigned int cvtpk(float lo, float hi) {
  unsigned int r;
  asm("v_cvt_pk_bf16_f32 %0, %1, %2" : "=v"(r) : "v"(lo), "v"(hi));
  return r;
}

static __device__ __forceinline__ f32x4 mfma16(s16x8 a, s16x8 b, f32x4 c) {
  return __builtin_amdgcn_mfma_f32_16x16x32_bf16(a, b, c, 0, 0, 0);
}

// ---------------- convert x (fp32 -> bf16), 4 elems/thread ----------------
__global__ __launch_bounds__(256) void k_cvt_x(const float* __restrict__ x,
                                               unsigned short* __restrict__ xh) {
  int i = blockIdx.x * 256 + threadIdx.x;
  float4 v = ((const float4*)x)[i];
  ushort4 h;
  h.x = f2bf(v.x); h.y = f2bf(v.y); h.z = f2bf(v.z); h.w = f2bf(v.w);
  ((ushort4*)xh)[i] = h;
}

// ------- transpose-convert 4 weights in one launch (z selects W) -------
// z<3: into stacked WTqkv [3072 out][1024 in]; z==3: WTo [1024][1024].
__global__ void k_cvt_w4(const float* __restrict__ Wq, const float* __restrict__ Wk,
                         const float* __restrict__ Wv, const float* __restrict__ Wo,
                         unsigned short* __restrict__ WTqkv,
                         unsigned short* __restrict__ WTo) {
  __shared__ float t[32][33];
  int z = blockIdx.z;
  const float* W = z == 0 ? Wq : (z == 1 ? Wk : (z == 2 ? Wv : Wo));
  unsigned short* dst = z < 3 ? WTqkv + (size_t)z * 1024 * 1024 : WTo;
  int tx = threadIdx.x, ty = threadIdx.y;          // 32 x 8
  int bx = blockIdx.x * 32, by = blockIdx.y * 32;  // bx: out cols, by: in rows
  #pragma unroll
  for (int i = 0; i < 4; i++)
    t[ty + 8 * i][tx] = W[(size_t)(by + ty + 8 * i) * DM + bx + tx];
  __syncthreads();
  #pragma unroll
  for (int i = 0; i < 4; i++)
    dst[(size_t)(bx + ty + 8 * i) * DM + by + tx] = f2bf(t[tx][ty + 8 * i]);
}

// ---------------- 128x128 GEMM, compile-time MODE epilogue ----------------
// A: [8192][1024] bf16 row-major. BT: [1024 out][1024 in] bf16.
// MODE 0: Q -> [B,H,S,DK] bf16, *QSCALE;  1: K -> [B,H,S,DK] bf16;
// MODE 2: V -> [B,H,DK,S] bf16 (transposed); 3: fp32 out [8192][1024], nt.
template <int MODE>
__global__ __launch_bounds__(256) void k_projT(const unsigned short* __restrict__ A,
                                               const unsigned short* __restrict__ BT,
                                               const float* __restrict__ bias,
                                               void* __restrict__ outp) {
  __shared__ unsigned short lA[128 * 32];
  __shared__ unsigned short lB[128 * 32];
  const int tid = threadIdx.x;
  const int lane = tid & 63, wv = tid >> 6;
  const int wy = wv >> 1, wx = wv & 1;  // 2x2 waves, each 64x64 out
  const int l15 = lane & 15, l4 = lane >> 4;
  const int bm = blockIdx.y * 128, bn = blockIdx.x * 128;

  const f32x4 fz = {0.f, 0.f, 0.f, 0.f};
  f32x4 acc[4][4];
  #pragma unroll
  for (int i = 0; i < 4; i++)
    #pragma unroll
    for (int j = 0; j < 4; j++) acc[i][j] = fz;

  for (int k0 = 0; k0 < DM; k0 += 32) {
    #pragma unroll
    for (int r = 0; r < 2; r++) {
      int chunk = r * 256 + tid;
      int row = chunk >> 2, c4 = chunk & 3;  // [128 rows][32 cols], 16B chunks
      gload16(A + (size_t)(bm + row) * DM + k0 + c4 * 8,
              (char*)lA + (r * 256 + wv * 64) * 16);
      gload16(BT + (size_t)(bn + row) * DM + k0 + c4 * 8,
              (char*)lB + (r * 256 + wv * 64) * 16);
    }
    __syncthreads();
    s16x8 af[4], bf[4];
    #pragma unroll
    for (int i = 0; i < 4; i++)
      af[i] = *(const s16x8*)&lA[(wy * 64 + i * 16 + l15) * 32 + l4 * 8];
    #pragma unroll
    for (int j = 0; j < 4; j++)
      bf[j] = *(const s16x8*)&lB[(wx * 64 + j * 16 + l15) * 32 + l4 * 8];
    #pragma unroll
    for (int i = 0; i < 4; i++)
      #pragma unroll
      for (int j = 0; j < 4; j++)
        acc[i][j] = mfma16(af[i], bf[j], acc[i][j]);
    __syncthreads();
  }

  // C/D: col = lane&15, row = (lane>>4)*4 + reg
  #pragma unroll
  for (int j = 0; j < 4; j++) {
    int c = bn + wx * 64 + j * 16 + l15;
    float bvv = bias[c];
    int h = c >> 6, d = c & 63;
    #pragma unroll
    for (int i = 0; i < 4; i++) {
      int rbase = bm + wy * 64 + i * 16 + l4 * 4;
      #pragma unroll
      for (int r = 0; r < 4; r++) {
        float v = acc[i][j][r] + bvv;
        int row = rbase + r;
        int b = row >> 11, s = row & 2047;
        if (MODE == 0) {
          ((unsigned short*)outp)[(((size_t)(b * NH + h)) * SS + s) * DK + d] =
              f2bf(v * QSCALE);
        } else if (MODE == 1) {
          ((unsigned short*)outp)[(((size_t)(b * NH + h)) * SS + s) * DK + d] = f2bf(v);
        } else if (MODE == 2) {
          ((unsigned short*)outp)[(((size_t)(b * NH + h)) * DK + d) * SS + s] = f2bf(v);
        } else {
          __builtin_nontemporal_store(v, (float*)outp + (size_t)row * DM + c);
        }
      }
    }
  }
}

// ---------------- fused attention, swapped-QK, raw barriers ----------------
// Qh,Kh: [BH][S][DK] bf16 (Q pre-scaled QSCALE => scores in log2 domain).
// VhT: [BH][DK][S] bf16. attnO: [BH][S][S] fp32 (nt). AOh: [B][S][DM] bf16.
__global__ __launch_bounds__(256, 2) void k_attn(const unsigned short* __restrict__ Qh,
                                                 const unsigned short* __restrict__ Kh,
                                                 const unsigned short* __restrict__ VhT,
                                                 float* __restrict__ attnO,
                                                 unsigned short* __restrict__ AOh) {
  __shared__ unsigned short sm[4 * 128 * 64];

  const int tid = threadIdx.x;
  const int lane = tid & 63, wv = tid >> 6;
  const int l15 = lane & 15, l4 = lane >> 4;
  const int bh = blockIdx.y;
  const int q0 = blockIdx.x * 128;
  const size_t kbase = (size_t)bh * SS * DK;
  const f32x4 fz = {0.f, 0.f, 0.f, 0.f};

  auto stageK = [&](int kt, unsigned short* dst) {
    #pragma unroll
    for (int r = 0; r < 4; r++) {
      int chunk = r * 256 + tid;
      int row = chunk >> 3, c = chunk & 7;
      int cs = c ^ (row & 7);
      gload16(Kh + kbase + (size_t)(kt * 128 + row) * DK + cs * 8,
              (char*)dst + (r * 256 + wv * 64) * 16);
    }
  };
  auto stageV = [&](int kt, unsigned short* dst) {
    #pragma unroll
    for (int r = 0; r < 4; r++) {
      int chunk = r * 256 + tid;
      int row = chunk >> 4, c = chunk & 15;
      int cs = c ^ (row & 15);
      gload16(VhT + kbase + (size_t)row * SS + kt * 128 + cs * 8,
              (char*)dst + (r * 256 + wv * 64) * 16);
    }
  };

  // Q fragments (wave owns 32 q-rows)
  s16x8 qf[2][2];
  #pragma unroll
  for (int qt = 0; qt < 2; qt++)
    #pragma unroll
    for (int ks = 0; ks < 2; ks++) {
      int row = q0 + wv * 32 + qt * 16 + l15;
      qf[qt][ks] = *(const s16x8*)&Qh[kbase + (size_t)row * DK + ks * 32 + l4 * 8];
    }

  // ---- Pass A: row sums of 2^s. Lane-local keys {16nt + 4*l4 + r}. ----
  float lsA[2] = {0.f, 0.f};
  stageK(0, sm);
  stageK(1, sm + 8192);
  asm volatile("s_waitcnt vmcnt(4)" ::: "memory");
  __builtin_amdgcn_s_barrier();
  for (int kt = 0; kt < 16; kt++) {
    const unsigned short* kb = sm + (kt & 3) * 8192;
    if (kt < 14) stageK(kt + 2, sm + ((kt + 2) & 3) * 8192);
    #pragma unroll
    for (int nt = 0; nt < 8; nt++) {
      int krow = nt * 16 + l15;
      s16x8 kf0 = *(const s16x8*)&kb[krow * 64 + ((l4) ^ (krow & 7)) * 8];
      s16x8 kf1 = *(const s16x8*)&kb[krow * 64 + ((4 + l4) ^ (krow & 7)) * 8];
      #pragma unroll
      for (int qt = 0; qt < 2; qt++) {
        f32x4 s = fz;
        s = mfma16(kf0, qf[qt][0], s);
        s = mfma16(kf1, qf[qt][1], s);
        lsA[qt] += exp2f(s[0]) + exp2f(s[1]) + exp2f(s[2]) + exp2f(s[3]);
      }
    }
    if (kt < 14)
      asm volatile("s_waitcnt vmcnt(4)" ::: "memory");
    else
      asm volatile("s_waitcnt vmcnt(0)" ::: "memory");
    __builtin_amdgcn_s_barrier();
  }

  float l2l[2];
  #pragma unroll
  for (int qt = 0; qt < 2; qt++) {
    float v = lsA[qt];
    v += __shfl_xor(v, 16);
    v += __shfl_xor(v, 32);
    l2l[qt] = -log2f(v);  // p = 2^(s + l2l)
  }

  // ---- Pass B ----
  f32x4 oacc[2][4];
  #pragma unroll
  for (int qt = 0; qt < 2; qt++)
    #pragma unroll
    for (int dt = 0; dt < 4; dt++) oacc[qt][dt] = fz;

  float* ap0 = attnO + ((size_t)bh * SS + q0 + wv * 32 + l15) * SS;
  float* ap1 = ap0 + (size_t)16 * SS;

  stageK(0, sm);
  stageV(0, sm + 16384);
  asm volatile("s_waitcnt vmcnt(0)" ::: "memory");
  __builtin_amdgcn_s_barrier();

  for (int kt = 0; kt < 16; kt++) {
    const unsigned short* lk = sm + (kt & 1) * 8192;
    const unsigned short* lv = sm + 16384 + (kt & 1) * 8192;
    if (kt < 15) {
      stageK(kt + 1, sm + ((kt + 1) & 1) * 8192);
      stageV(kt + 1, sm + 16384 + ((kt + 1) & 1) * 8192);
    }

    // QK phase: lane holds p for keys kt*128 + nt*16 + 4*l4 + {0..3}, q = l15(+qt*16)
    unsigned int pw[2][8][2];
    #pragma unroll
    for (int nt = 0; nt < 8; nt++) {
      int krow = nt * 16 + l15;
      s16x8 kf0 = *(const s16x8*)&lk[krow * 64 + ((l4) ^ (krow & 7)) * 8];
      s16x8 kf1 = *(const s16x8*)&lk[krow * 64 + ((4 + l4) ^ (krow & 7)) * 8];
      #pragma unroll
      for (int qt = 0; qt < 2; qt++) {
        f32x4 s = fz;
        s = mfma16(kf0, qf[qt][0], s);
        s = mfma16(kf1, qf[qt][1], s);
        f32x4 p;
        p[0] = exp2f(s[0] + l2l[qt]);
        p[1] = exp2f(s[1] + l2l[qt]);
        p[2] = exp2f(s[2] + l2l[qt]);
        p[3] = exp2f(s[3] + l2l[qt]);
        float* ap = (qt == 0 ? ap0 : ap1) + kt * 128 + nt * 16 + l4 * 4;
        __builtin_nontemporal_store(p, (f32x4*)ap);
        pw[qt][nt][0] = cvtpk(p[0], p[1]);
        pw[qt][nt][1] = cvtpk(p[2], p[3]);
      }
    }

    // PV phase: k-slot permutation kappa(8g+4u+m) = 16u+4g+m on both P and V.
    #pragma unroll
    for (int ks = 0; ks < 4; ks++) {
      s16x8 vf[4];
      #pragma unroll
      for (int dt = 0; dt < 4; dt++) {
        int vrow = dt * 16 + l15;
        int c0 = (4 * ks + (l4 >> 1)) ^ (vrow & 15);
        int c1 = (4 * ks + 2 + (l4 >> 1)) ^ (vrow & 15);
        union { unsigned long long q[2]; s16x8 v; } vv;
        vv.q[0] = *(const unsigned long long*)&lv[vrow * 128 + c0 * 8 + (l4 & 1) * 4];
        vv.q[1] = *(const unsigned long long*)&lv[vrow * 128 + c1 * 8 + (l4 & 1) * 4];
        vf[dt] = vv.v;
      }
      #pragma unroll
      for (int qt = 0; qt < 2; qt++) {
        union { unsigned int u[4]; s16x8 v; } pa;
        pa.u[0] = pw[qt][2 * ks][0];
        pa.u[1] = pw[qt][2 * ks][1];
        pa.u[2] = pw[qt][2 * ks + 1][0];
        pa.u[3] = pw[qt][2 * ks + 1][1];
        #pragma unroll
        for (int dt = 0; dt < 4; dt++)
          oacc[qt][dt] = mfma16(pa.v, vf[dt], oacc[qt][dt]);
      }
    }

    // 8 loads (issued at top) are older than this tile's 16 stores:
    // vmcnt(16) => loads retired; stores stream on.
    asm volatile("s_waitcnt vmcnt(16)" ::: "memory");
    __builtin_amdgcn_s_barrier();
  }

  const int b = bh >> 4, h = bh & 15;
  const size_t aob = ((size_t)b * SS + q0 + wv * 32) * DM + h * DK;
  #pragma unroll
  for (int qt = 0; qt < 2; qt++)
    #pragma unroll
    for (int dt = 0; dt < 4; dt++)
      #pragma unroll
      for (int r = 0; r < 4; r++)
        AOh[aob + (size_t)(qt * 16 + l4 * 4 + r) * DM + dt * 16 + l15] =
            f2bf(oacc[qt][dt][r]);
}

extern "C" void kernel_launch(void* const* d_in, const int* in_sizes, int n_in,
                              void* d_out, int out_size, void* d_ws, size_t ws_size,
                              hipStream_t stream) {
  const float* x  = (const float*)d_in[0];
  const float* Wq = (const float*)d_in[1];
  const float* bq = (const float*)d_in[2];
  const float* Wk = (const float*)d_in[3];
  const float* bk = (const float*)d_in[4];
  const float* Wv = (const float*)d_in[5];
  const float* bv = (const float*)d_in[6];
  const float* Wo = (const float*)d_in[7];
  const float* bo = (const float*)d_in[8];

  char* ws = (char*)d_ws;
  // xh 16MB | WTqkv 6MB | WTo 2MB | Qh 16MB | Kh 16MB | VhT 16MB
  unsigned short* xh    = (unsigned short*)(ws);
  unsigned short* WTqkv = (unsigned short*)(ws + 16777216);
  unsigned short* WTo   = (unsigned short*)(ws + 16777216 + 6291456);
  unsigned short* Qh    = (unsigned short*)(ws + 25165824);
  unsigned short* Kh    = (unsigned short*)(ws + 25165824 + 1 * 16777216);
  unsigned short* VhT   = (unsigned short*)(ws + 25165824 + 2 * 16777216);
  unsigned short* AOh   = xh;  // alias: x_bf16 dead after projections

  float* outO  = (float*)d_out;
  float* attnO = (float*)d_out + (size_t)NB * SS * DM;

  k_cvt_x<<<8192, 256, 0, stream>>>(x, xh);
  dim3 tb(32, 8), tg(32, 32, 4);
  k_cvt_w4<<<tg, tb, 0, stream>>>(Wq, Wk, Wv, Wo, WTqkv, WTo);

  dim3 pg(8, 64);
  k_projT<0><<<pg, 256, 0, stream>>>(xh, WTqkv + 0 * 1048576, bq, Qh);
  k_projT<1><<<pg, 256, 0, stream>>>(xh, WTqkv + 1 * 1048576, bk, Kh);
  k_projT<2><<<pg, 256, 0, stream>>>(xh, WTqkv + 2 * 1048576, bv, VhT);

  // PROBE: run k_attn twice (idempotent — identical outputs). The dur delta
  // vs the single-run baseline (~548 us) measures T_attn in situ.
  dim3 ag(16, 64);
  k_attn<<<ag, 256, 0, stream>>>(Qh, Kh, VhT, attnO, AOh);
  k_attn<<<ag, 256, 0, stream>>>(Qh, Kh, VhT, attnO, AOh);

  k_projT<3><<<pg, 256, 0, stream>>>(AOh, WTo, bo, outO);
}

// Round 8
// 519.806 us; speedup vs baseline: 1.8900x; 1.8900x over previous
//
#include <hip/hip_runtime.h>
#include <stdint.h>

#define DM 1024
#define NH 16
#define DK 64
#define NB 4
#define SS 2048

// Q pre-scale: (1/sqrt(64)) * log2(e) so scores are in log2 domain.
#define QSCALE 0.18033688011112042f

typedef float f32x4 __attribute__((ext_vector_type(4)));
typedef short s16x8 __attribute__((ext_vector_type(8)));

typedef __attribute__((address_space(1))) unsigned int glb_u32;
typedef __attribute__((address_space(3))) unsigned int lds_u32;

static __device__ __forceinline__ void gload16(const void* g, void* lds) {
  __builtin_amdgcn_global_load_lds((glb_u32*)g, (lds_u32*)lds, 16, 0, 0);
}

static __device__ __forceinline__ unsigned short f2bf(float f) {
  union { float f; unsigned int u; } v;
  v.f = f;
  unsigned int u = v.u + 0x7fffu + ((v.u >> 16) & 1u);  // RNE
  return (unsigned short)(u >> 16);
}

static __device__ __forceinline__ unsigned int cvtpk(float lo, float hi) {
  unsigned int r;
  asm("v_cvt_pk_bf16_f32 %0, %1, %2" : "=v"(r) : "v"(lo), "v"(hi));
  return r;
}

static __device__ __forceinline__ f32x4 mfma16(s16x8 a, s16x8 b, f32x4 c) {
  return __builtin_amdgcn_mfma_f32_16x16x32_bf16(a, b, c, 0, 0, 0);
}

// ---------------- convert x (fp32 -> bf16), 4 elems/thread ----------------
__global__ __launch_bounds__(256) void k_cvt_x(const float* __restrict__ x,
                                               unsigned short* __restrict__ xh) {
  int i = blockIdx.x * 256 + threadIdx.x;
  float4 v = ((const float4*)x)[i];
  ushort4 h;
  h.x = f2bf(v.x); h.y = f2bf(v.y); h.z = f2bf(v.z); h.w = f2bf(v.w);
  ((ushort4*)xh)[i] = h;
}

// ------- transpose-convert 4 weights in one launch (z selects W) -------
__global__ void k_cvt_w4(const float* __restrict__ Wq, const float* __restrict__ Wk,
                         const float* __restrict__ Wv, const float* __restrict__ Wo,
                         unsigned short* __restrict__ WTqkv,
                         unsigned short* __restrict__ WTo) {
  __shared__ float t[32][33];
  int z = blockIdx.z;
  const float* W = z == 0 ? Wq : (z == 1 ? Wk : (z == 2 ? Wv : Wo));
  unsigned short* dst = z < 3 ? WTqkv + (size_t)z * 1024 * 1024 : WTo;
  int tx = threadIdx.x, ty = threadIdx.y;          // 32 x 8
  int bx = blockIdx.x * 32, by = blockIdx.y * 32;  // bx: out cols, by: in rows
  #pragma unroll
  for (int i = 0; i < 4; i++)
    t[ty + 8 * i][tx] = W[(size_t)(by + ty + 8 * i) * DM + bx + tx];
  __syncthreads();
  #pragma unroll
  for (int i = 0; i < 4; i++)
    dst[(size_t)(bx + ty + 8 * i) * DM + by + tx] = f2bf(t[tx][ty + 8 * i]);
}

// ---------------- 128x128 GEMM, compile-time MODE epilogue ----------------
template <int MODE>
__global__ __launch_bounds__(256) void k_projT(const unsigned short* __restrict__ A,
                                               const unsigned short* __restrict__ BT,
                                               const float* __restrict__ bias,
                                               void* __restrict__ outp) {
  __shared__ unsigned short lA[128 * 32];
  __shared__ unsigned short lB[128 * 32];
  const int tid = threadIdx.x;
  const int lane = tid & 63, wv = tid >> 6;
  const int wy = wv >> 1, wx = wv & 1;  // 2x2 waves, each 64x64 out
  const int l15 = lane & 15, l4 = lane >> 4;
  const int bm = blockIdx.y * 128, bn = blockIdx.x * 128;

  const f32x4 fz = {0.f, 0.f, 0.f, 0.f};
  f32x4 acc[4][4];
  #pragma unroll
  for (int i = 0; i < 4; i++)
    #pragma unroll
    for (int j = 0; j < 4; j++) acc[i][j] = fz;

  for (int k0 = 0; k0 < DM; k0 += 32) {
    #pragma unroll
    for (int r = 0; r < 2; r++) {
      int chunk = r * 256 + tid;
      int row = chunk >> 2, c4 = chunk & 3;  // [128 rows][32 cols], 16B chunks
      gload16(A + (size_t)(bm + row) * DM + k0 + c4 * 8,
              (char*)lA + (r * 256 + wv * 64) * 16);
      gload16(BT + (size_t)(bn + row) * DM + k0 + c4 * 8,
              (char*)lB + (r * 256 + wv * 64) * 16);
    }
    __syncthreads();
    s16x8 af[4], bf[4];
    #pragma unroll
    for (int i = 0; i < 4; i++)
      af[i] = *(const s16x8*)&lA[(wy * 64 + i * 16 + l15) * 32 + l4 * 8];
    #pragma unroll
    for (int j = 0; j < 4; j++)
      bf[j] = *(const s16x8*)&lB[(wx * 64 + j * 16 + l15) * 32 + l4 * 8];
    #pragma unroll
    for (int i = 0; i < 4; i++)
      #pragma unroll
      for (int j = 0; j < 4; j++)
        acc[i][j] = mfma16(af[i], bf[j], acc[i][j]);
    __syncthreads();
  }

  // C/D: col = lane&15, row = (lane>>4)*4 + reg
  #pragma unroll
  for (int j = 0; j < 4; j++) {
    int c = bn + wx * 64 + j * 16 + l15;
    float bvv = bias[c];
    int h = c >> 6, d = c & 63;
    #pragma unroll
    for (int i = 0; i < 4; i++) {
      int rbase = bm + wy * 64 + i * 16 + l4 * 4;
      #pragma unroll
      for (int r = 0; r < 4; r++) {
        float v = acc[i][j][r] + bvv;
        int row = rbase + r;
        int b = row >> 11, s = row & 2047;
        if (MODE == 0) {
          ((unsigned short*)outp)[(((size_t)(b * NH + h)) * SS + s) * DK + d] =
              f2bf(v * QSCALE);
        } else if (MODE == 1) {
          ((unsigned short*)outp)[(((size_t)(b * NH + h)) * SS + s) * DK + d] = f2bf(v);
        } else if (MODE == 2) {
          ((unsigned short*)outp)[(((size_t)(b * NH + h)) * DK + d) * SS + s] = f2bf(v);
        } else {
          __builtin_nontemporal_store(v, (float*)outp + (size_t)row * DM + c);
        }
      }
    }
  }
}

// ---------------- fused attention, KVBLK=64, triple-buffered ----------------
// Qh,Kh: [BH][S][DK] bf16 (Q pre-scaled QSCALE => log2 domain).
// VhT: [BH][DK][S] bf16. attnO: [BH][S][S] fp32 (plain stores). AOh: bf16.
// LDS 48KB: K slots sm+{0,1,2}*4096, V slots sm+12288+{0,1,2}*4096 (shorts).
// Pass A: 4-slot K ring in sm[0..16383].
__global__ __launch_bounds__(256, 3) void k_attn(const unsigned short* __restrict__ Qh,
                                                 const unsigned short* __restrict__ Kh,
                                                 const unsigned short* __restrict__ VhT,
                                                 float* __restrict__ attnO,
                                                 unsigned short* __restrict__ AOh) {
  __shared__ unsigned short sm[24576];

  const int tid = threadIdx.x;
  const int lane = tid & 63, wv = tid >> 6;
  const int l15 = lane & 15, l4 = lane >> 4;
  const int bh = blockIdx.y;
  const int q0 = blockIdx.x * 128;
  const size_t kbase = (size_t)bh * SS * DK;
  const f32x4 fz = {0.f, 0.f, 0.f, 0.f};

  // K tile kt: 64 kv rows x 64 dk (128B/row, 8x16B chunks, swz c^=(row&7))
  auto stageK = [&](int kt, unsigned short* dst) {
    #pragma unroll
    for (int r = 0; r < 2; r++) {
      int chunk = r * 256 + tid;
      int row = chunk >> 3, c = chunk & 7;
      int cs = c ^ (row & 7);
      gload16(Kh + kbase + (size_t)(kt * 64 + row) * DK + cs * 8,
              (char*)dst + (r * 256 + wv * 64) * 16);
    }
  };
  // V tile kt: 64 dk rows x 64 kv (128B/row, swz c^=(row&7))
  auto stageV = [&](int kt, unsigned short* dst) {
    #pragma unroll
    for (int r = 0; r < 2; r++) {
      int chunk = r * 256 + tid;
      int row = chunk >> 3, c = chunk & 7;
      int cs = c ^ (row & 7);
      gload16(VhT + kbase + (size_t)row * SS + kt * 64 + cs * 8,
              (char*)dst + (r * 256 + wv * 64) * 16);
    }
  };

  // Q fragments (wave owns 32 q-rows)
  s16x8 qf[2][2];
  #pragma unroll
  for (int qt = 0; qt < 2; qt++)
    #pragma unroll
    for (int ks = 0; ks < 2; ks++) {
      int row = q0 + wv * 32 + qt * 16 + l15;
      qf[qt][ks] = *(const s16x8*)&Qh[kbase + (size_t)row * DK + ks * 32 + l4 * 8];
    }

  // ---- Pass A: row sums of 2^s ----
  float lsA[2] = {0.f, 0.f};
  stageK(0, sm);
  stageK(1, sm + 4096);
  asm volatile("s_waitcnt vmcnt(2)" ::: "memory");
  __builtin_amdgcn_s_barrier();
  for (int kt = 0; kt < 32; kt++) {
    const unsigned short* kb = sm + (kt & 3) * 4096;
    if (kt < 30) stageK(kt + 2, sm + ((kt + 2) & 3) * 4096);
    #pragma unroll
    for (int nt = 0; nt < 4; nt++) {
      int krow = nt * 16 + l15;
      s16x8 kf0 = *(const s16x8*)&kb[krow * 64 + ((l4) ^ (krow & 7)) * 8];
      s16x8 kf1 = *(const s16x8*)&kb[krow * 64 + ((4 + l4) ^ (krow & 7)) * 8];
      #pragma unroll
      for (int qt = 0; qt < 2; qt++) {
        f32x4 s = fz;
        s = mfma16(kf0, qf[qt][0], s);
        s = mfma16(kf1, qf[qt][1], s);
        lsA[qt] += exp2f(s[0]) + exp2f(s[1]) + exp2f(s[2]) + exp2f(s[3]);
      }
    }
    if (kt < 30)
      asm volatile("s_waitcnt vmcnt(2)" ::: "memory");
    else
      asm volatile("s_waitcnt vmcnt(0)" ::: "memory");
    __builtin_amdgcn_s_barrier();
  }

  float l2l[2];
  #pragma unroll
  for (int qt = 0; qt < 2; qt++) {
    float v = lsA[qt];
    v += __shfl_xor(v, 16);
    v += __shfl_xor(v, 32);
    l2l[qt] = -log2f(v);  // p = 2^(s + l2l)
  }

  // ---- Pass B ----
  f32x4 oacc[2][4];
  #pragma unroll
  for (int qt = 0; qt < 2; qt++)
    #pragma unroll
    for (int dt = 0; dt < 4; dt++) oacc[qt][dt] = fz;

  float* ap0 = attnO + ((size_t)bh * SS + q0 + wv * 32 + l15) * SS;
  float* ap1 = ap0 + (size_t)16 * SS;

  stageK(0, sm);
  stageV(0, sm + 12288);
  stageK(1, sm + 4096);
  stageV(1, sm + 12288 + 4096);
  asm volatile("s_waitcnt vmcnt(4)" ::: "memory");
  __builtin_amdgcn_s_barrier();

  for (int kt = 0; kt < 32; kt++) {
    int sl = kt % 3;
    const unsigned short* lk = sm + sl * 4096;
    const unsigned short* lv = sm + 12288 + sl * 4096;
    if (kt < 30) {
      int s2 = (kt + 2) % 3;
      stageK(kt + 2, sm + s2 * 4096);
      stageV(kt + 2, sm + 12288 + s2 * 4096);
    }

    // QK phase: lane holds p for keys kt*64 + nt*16 + 4*l4 + {0..3}, q = l15(+qt*16)
    unsigned int pw[2][4][2];
    #pragma unroll
    for (int nt = 0; nt < 4; nt++) {
      int krow = nt * 16 + l15;
      s16x8 kf0 = *(const s16x8*)&lk[krow * 64 + ((l4) ^ (krow & 7)) * 8];
      s16x8 kf1 = *(const s16x8*)&lk[krow * 64 + ((4 + l4) ^ (krow & 7)) * 8];
      #pragma unroll
      for (int qt = 0; qt < 2; qt++) {
        f32x4 s = fz;
        s = mfma16(kf0, qf[qt][0], s);
        s = mfma16(kf1, qf[qt][1], s);
        f32x4 p;
        p[0] = exp2f(s[0] + l2l[qt]);
        p[1] = exp2f(s[1] + l2l[qt]);
        p[2] = exp2f(s[2] + l2l[qt]);
        p[3] = exp2f(s[3] + l2l[qt]);
        float* ap = (qt == 0 ? ap0 : ap1) + kt * 64 + nt * 16 + l4 * 4;
        *(f32x4*)ap = p;  // plain store (through L2, line-merged)
        pw[qt][nt][0] = cvtpk(p[0], p[1]);
        pw[qt][nt][1] = cvtpk(p[2], p[3]);
      }
    }

    // PV phase: kappa(slot 8g+4u+m) = 16u+4g+m on both P and V, per 32-key group
    #pragma unroll
    for (int ks = 0; ks < 2; ks++) {
      s16x8 vf[4];
      #pragma unroll
      for (int dt = 0; dt < 4; dt++) {
        int vrow = dt * 16 + l15;
        int c0 = (4 * ks + (l4 >> 1)) ^ (vrow & 7);
        int c1 = (4 * ks + 2 + (l4 >> 1)) ^ (vrow & 7);
        union { unsigned long long q[2]; s16x8 v; } vv;
        vv.q[0] = *(const unsigned long long*)&lv[vrow * 64 + c0 * 8 + (l4 & 1) * 4];
        vv.q[1] = *(const unsigned long long*)&lv[vrow * 64 + c1 * 8 + (l4 & 1) * 4];
        vf[dt] = vv.v;
      }
      #pragma unroll
      for (int qt = 0; qt < 2; qt++) {
        union { unsigned int u[4]; s16x8 v; } pa;
        pa.u[0] = pw[qt][2 * ks][0];
        pa.u[1] = pw[qt][2 * ks][1];
        pa.u[2] = pw[qt][2 * ks + 1][0];
        pa.u[3] = pw[qt][2 * ks + 1][1];
        #pragma unroll
        for (int dt = 0; dt < 4; dt++)
          oacc[qt][dt] = mfma16(pa.v, vf[dt], oacc[qt][dt]);
      }
    }

    // Triple buffer => wait retires ONLY the loads for tile kt+1, never stores:
    // younger-than-them = stores(kt-1) 8 + loads(kt+2) 4 + stores(kt) 8 = 20.
    if (kt == 0)
      asm volatile("s_waitcnt vmcnt(12)" ::: "memory");
    else if (kt < 30)
      asm volatile("s_waitcnt vmcnt(20)" ::: "memory");
    else if (kt == 30)
      asm volatile("s_waitcnt vmcnt(16)" ::: "memory");
    if (kt < 31) __builtin_amdgcn_s_barrier();
  }

  const int b = bh >> 4, h = bh & 15;
  const size_t aob = ((size_t)b * SS + q0 + wv * 32) * DM + h * DK;
  #pragma unroll
  for (int qt = 0; qt < 2; qt++)
    #pragma unroll
    for (int dt = 0; dt < 4; dt++)
      #pragma unroll
      for (int r = 0; r < 4; r++)
        AOh[aob + (size_t)(qt * 16 + l4 * 4 + r) * DM + dt * 16 + l15] =
            f2bf(oacc[qt][dt][r]);
}

extern "C" void kernel_launch(void* const* d_in, const int* in_sizes, int n_in,
                              void* d_out, int out_size, void* d_ws, size_t ws_size,
                              hipStream_t stream) {
  const float* x  = (const float*)d_in[0];
  const float* Wq = (const float*)d_in[1];
  const float* bq = (const float*)d_in[2];
  const float* Wk = (const float*)d_in[3];
  const float* bk = (const float*)d_in[4];
  const float* Wv = (const float*)d_in[5];
  const float* bv = (const float*)d_in[6];
  const float* Wo = (const float*)d_in[7];
  const float* bo = (const float*)d_in[8];

  char* ws = (char*)d_ws;
  unsigned short* xh    = (unsigned short*)(ws);
  unsigned short* WTqkv = (unsigned short*)(ws + 16777216);
  unsigned short* WTo   = (unsigned short*)(ws + 16777216 + 6291456);
  unsigned short* Qh    = (unsigned short*)(ws + 25165824);
  unsigned short* Kh    = (unsigned short*)(ws + 25165824 + 1 * 16777216);
  unsigned short* VhT   = (unsigned short*)(ws + 25165824 + 2 * 16777216);
  unsigned short* AOh   = xh;  // alias: x_bf16 dead after projections

  float* outO  = (float*)d_out;
  float* attnO = (float*)d_out + (size_t)NB * SS * DM;

  k_cvt_x<<<8192, 256, 0, stream>>>(x, xh);
  dim3 tb(32, 8), tg(32, 32, 4);
  k_cvt_w4<<<tg, tb, 0, stream>>>(Wq, Wk, Wv, Wo, WTqkv, WTo);

  dim3 pg(8, 64);
  k_projT<0><<<pg, 256, 0, stream>>>(xh, WTqkv + 0 * 1048576, bq, Qh);
  k_projT<1><<<pg, 256, 0, stream>>>(xh, WTqkv + 1 * 1048576, bk, Kh);
  k_projT<2><<<pg, 256, 0, stream>>>(xh, WTqkv + 2 * 1048576, bv, VhT);

  dim3 ag(16, 64);
  k_attn<<<ag, 256, 0, stream>>>(Qh, Kh, VhT, attnO, AOh);

  k_projT<3><<<pg, 256, 0, stream>>>(AOh, WTo, bo, outO);
}